// Round 1
// baseline (334.091 us; speedup 1.0000x reference)
//
#include <hip/hip_runtime.h>

// ---------------------------------------------------------------------------
// GMMConv forward:
//   node_feat = feat @ W_fc.T                      [N, K*F]  (K=4, F=64)
//   g[e,k]    = exp(-0.5 * sum_d (pseudo[e,d]-mu[k,d])^2 * inv_sigma[k,d]^2)
//   msg[e,f]  = sum_k g[e,k] * node_feat[colind[e], k*F+f]
//   out[r,f]  = sum_{e in [rowptr[r],rowptr[r+1])} msg[e,f] + bias[f]
// CSR rowptr sorts edges by destination -> one wave per destination node,
// lane = f, no atomics needed.
// node_feat stored as bf16 in workspace (25.6 MB) to halve gather traffic;
// absmax tolerance (~2% of output magnitude) dwarfs bf16 rounding.
// ---------------------------------------------------------------------------

#define TM 128
#define TN 128
#define TK 8
#define KDIM 256   // IN
#define JDIM 256   // K*F

__device__ inline unsigned short f32_to_bf16(float f) {
    union { float f; unsigned int u; } c; c.f = f;
    unsigned int u = c.u;
    u += 0x7fffu + ((u >> 16) & 1u);   // round-to-nearest-even
    return (unsigned short)(u >> 16);
}
__device__ inline float bf16_to_f32(unsigned short h) {
    union { unsigned int u; float f; } c; c.u = ((unsigned int)h) << 16;
    return c.f;
}

// C[m][j] = sum_k A[m][k] * B[j][k]; C written as bf16.
// 256 threads, 128x128 tile, 8x8 microtile per thread.
__global__ __launch_bounds__(256) void gemm_proj(
    const float* __restrict__ A,        // feat [M][256]
    const float* __restrict__ B,        // W_fc [256][256]
    unsigned short* __restrict__ C,     // node_feat bf16 [M][256]
    int M)
{
    __shared__ float As[TK][TM + 4];
    __shared__ float Bs[TK][TN + 4];
    const int t  = threadIdx.x;
    const int tx = t & 15;
    const int ty = t >> 4;
    const int bm = blockIdx.x * TM;
    const int bn = blockIdx.y * TN;
    const int lrow = t >> 1;            // 0..127
    const int lk   = (t & 1) << 2;      // 0 or 4

    float acc[8][8];
#pragma unroll
    for (int i = 0; i < 8; ++i)
#pragma unroll
        for (int j = 0; j < 8; ++j) acc[i][j] = 0.f;

    const int arow = bm + lrow;
    const int brow = bn + lrow;         // always < 256

    for (int k0 = 0; k0 < KDIM; k0 += TK) {
        float4 av = make_float4(0.f, 0.f, 0.f, 0.f);
        if (arow < M)
            av = *reinterpret_cast<const float4*>(A + (size_t)arow * KDIM + k0 + lk);
        const float4 bv = *reinterpret_cast<const float4*>(B + (size_t)brow * KDIM + k0 + lk);

        __syncthreads();                // previous iteration done reading LDS
        As[lk + 0][lrow] = av.x;
        As[lk + 1][lrow] = av.y;
        As[lk + 2][lrow] = av.z;
        As[lk + 3][lrow] = av.w;
        Bs[lk + 0][lrow] = bv.x;
        Bs[lk + 1][lrow] = bv.y;
        Bs[lk + 2][lrow] = bv.z;
        Bs[lk + 3][lrow] = bv.w;
        __syncthreads();

#pragma unroll
        for (int kk = 0; kk < TK; ++kk) {
            const float4 a0 = *reinterpret_cast<const float4*>(&As[kk][ty * 8]);
            const float4 a1 = *reinterpret_cast<const float4*>(&As[kk][ty * 8 + 4]);
            const float4 b0 = *reinterpret_cast<const float4*>(&Bs[kk][tx * 8]);
            const float4 b1 = *reinterpret_cast<const float4*>(&Bs[kk][tx * 8 + 4]);
            const float a[8] = {a0.x, a0.y, a0.z, a0.w, a1.x, a1.y, a1.z, a1.w};
            const float b[8] = {b0.x, b0.y, b0.z, b0.w, b1.x, b1.y, b1.z, b1.w};
#pragma unroll
            for (int i = 0; i < 8; ++i)
#pragma unroll
                for (int j = 0; j < 8; ++j)
                    acc[i][j] += a[i] * b[j];
        }
    }

    const int m0 = bm + ty * 8;
    const int j0 = bn + tx * 8;
#pragma unroll
    for (int i = 0; i < 8; ++i) {
        const int m = m0 + i;
        if (m < M) {
            union { uint4 v; unsigned short s[8]; } pk;
#pragma unroll
            for (int j = 0; j < 8; ++j) pk.s[j] = f32_to_bf16(acc[i][j]);
            *reinterpret_cast<uint4*>(C + (size_t)m * JDIM + j0) = pk.v;
        }
    }
}

// One wave per destination node; lane = feature index f (F=64).
__global__ __launch_bounds__(256) void edge_aggregate(
    const int* __restrict__ rowptr,
    const int* __restrict__ colind,
    const float* __restrict__ pseudo,       // [E][2]
    const unsigned short* __restrict__ nf,  // node_feat bf16 [N][256]
    const float* __restrict__ mu,           // [4][2]
    const float* __restrict__ inv_sigma,    // [4][2]
    const float* __restrict__ bias,         // [64]
    float* __restrict__ out,                // [N][64]
    int N)
{
    const int gid  = blockIdx.x * blockDim.x + threadIdx.x;
    const int node = gid >> 6;
    const int lane = gid & 63;
    if (node >= N) return;

    float mx[4], my[4], sx[4], sy[4];
#pragma unroll
    for (int k = 0; k < 4; ++k) {
        mx[k] = mu[2 * k];
        my[k] = mu[2 * k + 1];
        const float a = inv_sigma[2 * k];
        const float b = inv_sigma[2 * k + 1];
        sx[k] = a * a;
        sy[k] = b * b;
    }

    const int e0 = rowptr[node];
    const int e1 = rowptr[node + 1];
    const float2* ps = reinterpret_cast<const float2*>(pseudo);

    float acc = 0.f;
    for (int e = e0; e < e1; ++e) {
        const int col = colind[e];
        const float2 p = ps[e];
        const unsigned short* q = nf + (size_t)col * 256 + lane;
#pragma unroll
        for (int k = 0; k < 4; ++k) {
            const float dx = p.x - mx[k];
            const float dy = p.y - my[k];
            const float g = __expf(-0.5f * (dx * dx * sx[k] + dy * dy * sy[k]));
            acc += g * bf16_to_f32(q[k * 64]);
        }
    }
    out[(size_t)node * 64 + lane] = acc + bias[lane];
}

extern "C" void kernel_launch(void* const* d_in, const int* in_sizes, int n_in,
                              void* d_out, int out_size, void* d_ws, size_t ws_size,
                              hipStream_t stream)
{
    const int*   rowptr    = (const int*)d_in[0];
    const int*   colind    = (const int*)d_in[1];
    // d_in[2] colptr, d_in[3] rowind, d_in[4] permute: unused in forward math
    const float* feat      = (const float*)d_in[5];
    const float* pseudo    = (const float*)d_in[6];
    const float* W_fc      = (const float*)d_in[7];
    const float* mu        = (const float*)d_in[8];
    const float* inv_sigma = (const float*)d_in[9];
    const float* bias      = (const float*)d_in[10];
    float* out = (float*)d_out;
    unsigned short* nf = (unsigned short*)d_ws;   // 50000*256*2 = 25.6 MB

    const int N = in_sizes[0] - 1;   // 50000

    dim3 gGemm((N + TM - 1) / TM, JDIM / TN);
    hipLaunchKernelGGL(gemm_proj, gGemm, dim3(256), 0, stream, feat, W_fc, nf, N);

    const int blocks = (N + 3) / 4;  // 4 waves (nodes) per 256-thread block
    hipLaunchKernelGGL(edge_aggregate, dim3(blocks), dim3(256), 0, stream,
                       rowptr, colind, pseudo, nf, mu, inv_sigma, bias, out, N);
}

// Round 2
// 202.606 us; speedup vs baseline: 1.6490x; 1.6490x over previous
//
#include <hip/hip_runtime.h>

// ---------------------------------------------------------------------------
// GMMConv forward, two kernels:
//  1) gemm_mfma: node_feat = feat @ W_fc.T via bf16 MFMA 16x16x32, output
//     stored bf16 in PERMUTED layout nf[m][f*4+k]  (f=0..63, k=0..3) so the
//     edge kernel gathers each lane's 4 k-values with ONE ushort4 load.
//     Permutation is free: output column j' reads W row ((j'&3)<<6)|(j'>>2).
//  2) edge_aggregate: one wave per destination node (CSR rowptr sorts edges
//     by dst -> no atomics). Per 16-edge chunk, lane (ii,kk) computes one
//     gaussian -> LDS (64x fewer exp than all-lanes-redundant); inner loop
//     broadcasts g via b128 LDS read + one 8B coalesced nf gather per lane.
// ---------------------------------------------------------------------------

typedef __attribute__((ext_vector_type(8))) short bf16x8;
typedef __attribute__((ext_vector_type(4))) float f32x4;

__device__ inline unsigned short f32_to_bf16(float f) {
    union { float f; unsigned int u; } c; c.f = f;
    unsigned int u = c.u;
    u += 0x7fffu + ((u >> 16) & 1u);   // round-to-nearest-even
    return (unsigned short)(u >> 16);
}
__device__ inline float bf16_to_f32(unsigned short h) {
    union { unsigned int u; float f; } c; c.u = ((unsigned int)h) << 16;
    return c.f;
}

#define LDST 40   // LDS row stride in bf16 elems (80 B: 16B-aligned, 2-way-free banks)

// C[m][j'] = sum_k A[m][k] * W[map(j')][k], C bf16, map(j') = ((j'&3)<<6)|(j'>>2)
__global__ __launch_bounds__(256, 2) void gemm_mfma(
    const float* __restrict__ A,        // feat [M][256] fp32
    const float* __restrict__ W,        // W_fc [256][256] fp32
    unsigned short* __restrict__ C,     // nf bf16 [M][256] permuted
    int M)
{
    __shared__ unsigned short As[128 * LDST];
    __shared__ unsigned short Bs[128 * LDST];
    const int t    = threadIdx.x;
    const int lane = t & 63;
    const int wave = t >> 6;
    const int wm   = (wave >> 1) * 64;
    const int wn   = (wave & 1) * 64;
    const int bm   = blockIdx.x * 128;
    const int bn   = blockIdx.y * 128;
    const int l16  = lane & 15;
    const int quad = lane >> 4;

    f32x4 acc[4][4];
#pragma unroll
    for (int mi = 0; mi < 4; ++mi)
#pragma unroll
        for (int ni = 0; ni < 4; ++ni)
            acc[mi][ni] = (f32x4){0.f, 0.f, 0.f, 0.f};

    for (int k0 = 0; k0 < 256; k0 += 32) {
        // stage 128x32 fp32 -> bf16 LDS (A and B), 4 float4 per thread each
#pragma unroll
        for (int i = 0; i < 4; ++i) {
            const int flat = (i * 256 + t) * 4;   // 0..4095
            const int row  = flat >> 5;           // 0..127
            const int off  = flat & 31;
            const int grow = bm + row;
            float4 av = make_float4(0.f, 0.f, 0.f, 0.f);
            if (grow < M)
                av = *reinterpret_cast<const float4*>(A + (size_t)grow * 256 + k0 + off);
            const int jp   = bn + row;
            const int wrow = ((jp & 3) << 6) | (jp >> 2);
            const float4 wv = *reinterpret_cast<const float4*>(W + (size_t)wrow * 256 + k0 + off);
            ushort4 ah, wh;
            ah.x = f32_to_bf16(av.x); ah.y = f32_to_bf16(av.y);
            ah.z = f32_to_bf16(av.z); ah.w = f32_to_bf16(av.w);
            wh.x = f32_to_bf16(wv.x); wh.y = f32_to_bf16(wv.y);
            wh.z = f32_to_bf16(wv.z); wh.w = f32_to_bf16(wv.w);
            *reinterpret_cast<ushort4*>(&As[row * LDST + off]) = ah;
            *reinterpret_cast<ushort4*>(&Bs[row * LDST + off]) = wh;
        }
        __syncthreads();

        bf16x8 af[4], bfr[4];
#pragma unroll
        for (int mi = 0; mi < 4; ++mi)
            af[mi] = *reinterpret_cast<const bf16x8*>(&As[(wm + mi * 16 + l16) * LDST + quad * 8]);
#pragma unroll
        for (int ni = 0; ni < 4; ++ni)
            bfr[ni] = *reinterpret_cast<const bf16x8*>(&Bs[(wn + ni * 16 + l16) * LDST + quad * 8]);
#pragma unroll
        for (int mi = 0; mi < 4; ++mi)
#pragma unroll
            for (int ni = 0; ni < 4; ++ni)
                acc[mi][ni] = __builtin_amdgcn_mfma_f32_16x16x32_bf16(
                    af[mi], bfr[ni], acc[mi][ni], 0, 0, 0);
        __syncthreads();
    }

    // C/D layout: col = lane&15, row = quad*4 + reg   [m89-verified]
#pragma unroll
    for (int mi = 0; mi < 4; ++mi) {
#pragma unroll
        for (int r = 0; r < 4; ++r) {
            const int row = bm + wm + mi * 16 + quad * 4 + r;
            if (row < M) {
#pragma unroll
                for (int ni = 0; ni < 4; ++ni) {
                    const int col = bn + wn + ni * 16 + l16;
                    C[(size_t)row * 256 + col] = f32_to_bf16(acc[mi][ni][r]);
                }
            }
        }
    }
}

// One wave per destination node; lane = feature f (F=64).
__global__ __launch_bounds__(256) void edge_aggregate(
    const int* __restrict__ rowptr,
    const int* __restrict__ colind,
    const float* __restrict__ pseudo,       // [E][2]
    const unsigned short* __restrict__ nf,  // bf16 [N][256] permuted [f*4+k]
    const float* __restrict__ mu,           // [4][2]
    const float* __restrict__ inv_sigma,    // [4][2]
    const float* __restrict__ bias,         // [64]
    float* __restrict__ out,                // [N][64]
    int N)
{
    __shared__ float gbuf[4][64];   // per-wave: 16 edges x 4 kernels
    __shared__ int   cbuf[4][16];   // per-wave: 16 colinds
    const int wave = threadIdx.x >> 6;
    const int lane = threadIdx.x & 63;
    const int node = blockIdx.x * 4 + wave;
    if (node >= N) return;          // wave-uniform exit; no block barriers below

    const int kk = lane >> 4;       // gaussian kernel this lane computes
    const int ii = lane & 15;       // edge slot this lane computes
    const float mx = mu[2 * kk], my = mu[2 * kk + 1];
    const float sa = inv_sigma[2 * kk], sb = inv_sigma[2 * kk + 1];
    const float sx = sa * sa, sy = sb * sb;

    const int e0 = rowptr[node];
    const int e1 = rowptr[node + 1];

    float* gw = gbuf[wave];
    int*   cw = cbuf[wave];

    float acc = 0.f;
    for (int ec = e0; ec < e1; ec += 16) {
        const int cnt = min(16, e1 - ec);
        if (ii < cnt) {
            const int e = ec + ii;
            const float2 p = *reinterpret_cast<const float2*>(pseudo + 2 * (size_t)e);
            const float dx = p.x - mx, dy = p.y - my;
            gw[ii * 4 + kk] = __expf(-0.5f * (dx * dx * sx + dy * dy * sy));
            if (kk == 0) cw[ii] = colind[e];
        }
        __builtin_amdgcn_wave_barrier();
        __threadfence_block();      // drain LDS writes before broadcast reads
        for (int i2 = 0; i2 < cnt; ++i2) {
            const int col = cw[i2];
            const float4 g = *reinterpret_cast<const float4*>(&gw[i2 * 4]);
            const ushort4 h = *reinterpret_cast<const ushort4*>(
                nf + ((size_t)col << 8) + (lane << 2));
            acc += g.x * bf16_to_f32(h.x) + g.y * bf16_to_f32(h.y)
                 + g.z * bf16_to_f32(h.z) + g.w * bf16_to_f32(h.w);
        }
        __builtin_amdgcn_wave_barrier();
        __threadfence_block();      // reads done before next chunk's writes
    }
    out[((size_t)node << 6) + lane] = acc + bias[lane];
}

extern "C" void kernel_launch(void* const* d_in, const int* in_sizes, int n_in,
                              void* d_out, int out_size, void* d_ws, size_t ws_size,
                              hipStream_t stream)
{
    const int*   rowptr    = (const int*)d_in[0];
    const int*   colind    = (const int*)d_in[1];
    // d_in[2] colptr, d_in[3] rowind, d_in[4] permute: inert in forward math
    const float* feat      = (const float*)d_in[5];
    const float* pseudo    = (const float*)d_in[6];
    const float* W_fc      = (const float*)d_in[7];
    const float* mu        = (const float*)d_in[8];
    const float* inv_sigma = (const float*)d_in[9];
    const float* bias      = (const float*)d_in[10];
    float* out = (float*)d_out;
    unsigned short* nf = (unsigned short*)d_ws;   // 50000*256*2 = 25.6 MB

    const int N = in_sizes[0] - 1;   // 50000

    dim3 gGemm((N + 127) / 128, 2);
    hipLaunchKernelGGL(gemm_mfma, gGemm, dim3(256), 0, stream, feat, W_fc, nf, N);

    const int blocks = (N + 3) / 4;  // 4 waves (nodes) per 256-thread block
    hipLaunchKernelGGL(edge_aggregate, dim3(blocks), dim3(256), 0, stream,
                       rowptr, colind, pseudo, nf, mu, inv_sigma, bias, out, N);
}